// Round 1
// baseline (281.146 us; speedup 1.0000x reference)
//
#include <hip/hip_runtime.h>
#include <cstdint>
#include <cstddef>

// FusedBitLinear: RMSNorm -> ternary W quant (absmean) -> int8 activation quant
// -> int GEMM (MFMA i8) -> rescale by alpha*gamma/127.
//
// Shapes: x (2,2048,4096) fp32 -> tokens M=4096, K=4096; W (4096,4096) fp32;
// out (2,2048,4096) fp32.
//
// ws layout:
//   [0, 16M)            xq   int8 [4096][4096]
//   [16M, 32M)          wq   int8 [4096][4096]
//   [32M, +16KB)        gamma float[4096]
//   [+16KB, +32KB)      alpha partials float[4096]
//   [+32KB, +4B)        alpha float[1]

#define KD 4096
#define MD 4096
#define ND 4096

typedef int i32x4 __attribute__((ext_vector_type(4)));

// ---------------- alpha = max(mean(|W|), 1e-10) --------------------------

__global__ __launch_bounds__(256) void k_alpha_part(const float* __restrict__ w,
                                                    float* __restrict__ part) {
  __shared__ float red[256];
  const int tid = threadIdx.x;
  const float4* w4 = (const float4*)(w + (size_t)blockIdx.x * 4096);
  float s = 0.f;
#pragma unroll
  for (int i = 0; i < 4; ++i) {
    float4 v = w4[i * 256 + tid];
    s += fabsf(v.x) + fabsf(v.y) + fabsf(v.z) + fabsf(v.w);
  }
  red[tid] = s;
  __syncthreads();
  for (int st = 128; st > 0; st >>= 1) {
    if (tid < st) red[tid] += red[tid + st];
    __syncthreads();
  }
  if (tid == 0) part[blockIdx.x] = red[0];
}

__global__ __launch_bounds__(256) void k_alpha_final(const float* __restrict__ part,
                                                     float* __restrict__ alpha) {
  __shared__ float red[256];
  const int tid = threadIdx.x;
  float s = 0.f;
#pragma unroll
  for (int i = 0; i < 16; ++i) s += part[i * 256 + tid];
  red[tid] = s;
  __syncthreads();
  for (int st = 128; st > 0; st >>= 1) {
    if (tid < st) red[tid] += red[tid + st];
    __syncthreads();
  }
  if (tid == 0) alpha[0] = fmaxf(red[0] * (1.0f / 16777216.0f), 1e-10f);
}

// ---------------- w_q = clip(rint(w/alpha), -1, 1) as int8 ----------------

__global__ __launch_bounds__(256) void k_quant_w(const float* __restrict__ w,
                                                 const float* __restrict__ alpha_p,
                                                 signed char* __restrict__ wq) {
  const float alpha = alpha_p[0];
  const int tid = threadIdx.x;
  const float4* w4 = (const float4*)(w + (size_t)blockIdx.x * 4096);
  uint32_t* wqi = (uint32_t*)(wq + (size_t)blockIdx.x * 4096);
#pragma unroll
  for (int i = 0; i < 4; ++i) {
    const int f = i * 256 + tid;
    float4 v = w4[f];
    int q0 = (int)fminf(fmaxf(rintf(v.x / alpha), -1.f), 1.f);
    int q1 = (int)fminf(fmaxf(rintf(v.y / alpha), -1.f), 1.f);
    int q2 = (int)fminf(fmaxf(rintf(v.z / alpha), -1.f), 1.f);
    int q3 = (int)fminf(fmaxf(rintf(v.w / alpha), -1.f), 1.f);
    wqi[f] = (uint32_t)(q0 & 255) | ((uint32_t)(q1 & 255) << 8) |
             ((uint32_t)(q2 & 255) << 16) | ((uint32_t)(q3 & 255) << 24);
  }
}

// ------------- RMSNorm + gamma + int8 activation quant --------------------

__global__ __launch_bounds__(256) void k_rmsnorm_quant(const float* __restrict__ x,
                                                       const float* __restrict__ nw,
                                                       signed char* __restrict__ xq,
                                                       float* __restrict__ gamma) {
  __shared__ float red[256];
  const int tid = threadIdx.x;
  const int row = blockIdx.x;
  const float4* x4 = (const float4*)(x + (size_t)row * 4096);
  const float4* n4 = (const float4*)nw;
  float4 xv[4], nv[4];
  float ss = 0.f;
#pragma unroll
  for (int i = 0; i < 4; ++i) {
    xv[i] = x4[i * 256 + tid];
    nv[i] = n4[i * 256 + tid];
    ss += xv[i].x * xv[i].x + xv[i].y * xv[i].y + xv[i].z * xv[i].z + xv[i].w * xv[i].w;
  }
  red[tid] = ss;
  __syncthreads();
  for (int st = 128; st > 0; st >>= 1) {
    if (tid < st) red[tid] += red[tid + st];
    __syncthreads();
  }
  const float rms = sqrtf(red[0] * (1.0f / 4096.0f) + 1e-6f);
  __syncthreads();  // before red[] reuse

  float4 xn[4];
  float mx = 0.f;
#pragma unroll
  for (int i = 0; i < 4; ++i) {
    xn[i].x = xv[i].x / rms * nv[i].x;
    xn[i].y = xv[i].y / rms * nv[i].y;
    xn[i].z = xv[i].z / rms * nv[i].z;
    xn[i].w = xv[i].w / rms * nv[i].w;
    mx = fmaxf(mx, fmaxf(fmaxf(fabsf(xn[i].x), fabsf(xn[i].y)),
                         fmaxf(fabsf(xn[i].z), fabsf(xn[i].w))));
  }
  red[tid] = mx;
  __syncthreads();
  for (int st = 128; st > 0; st >>= 1) {
    if (tid < st) red[tid] = fmaxf(red[tid], red[tid + st]);
    __syncthreads();
  }
  const float g = fmaxf(red[0], 1e-10f);
  if (tid == 0) gamma[row] = g;

  uint32_t* xqi = (uint32_t*)(xq + (size_t)row * 4096);
#pragma unroll
  for (int i = 0; i < 4; ++i) {
    const int f = i * 256 + tid;
    int q0 = (int)fminf(fmaxf(rintf(xn[i].x * 127.0f / g), -128.f), 127.f);
    int q1 = (int)fminf(fmaxf(rintf(xn[i].y * 127.0f / g), -128.f), 127.f);
    int q2 = (int)fminf(fmaxf(rintf(xn[i].z * 127.0f / g), -128.f), 127.f);
    int q3 = (int)fminf(fmaxf(rintf(xn[i].w * 127.0f / g), -128.f), 127.f);
    xqi[f] = (uint32_t)(q0 & 255) | ((uint32_t)(q1 & 255) << 8) |
             ((uint32_t)(q2 & 255) << 16) | ((uint32_t)(q3 & 255) << 24);
  }
}

// ------------- int8 GEMM: y[m,n] = (xq . wq^T) * alpha*gamma[m]/127 -------
// 128x128 block tile, BK=64, 4 waves (2x2), each wave 64x64 via 4x4 MFMA
// 16x16x64 i8. A/B frag: element j of the 16 bytes = k = quad*16 + j,
// m/n = lane&15.  C/D: col = lane&15, row = quad*4 + reg (m89/m127 verified).

__global__ __launch_bounds__(256) void k_gemm(const signed char* __restrict__ xq,
                                              const signed char* __restrict__ wq,
                                              const float* __restrict__ gamma,
                                              const float* __restrict__ alpha_p,
                                              float* __restrict__ out) {
  __shared__ __align__(16) signed char As[128 * 64];
  __shared__ __align__(16) signed char Bs[128 * 64];
  const int tid = threadIdx.x;
  const int lane = tid & 63;
  const int wave = tid >> 6;
  const int wm = (wave >> 1) * 64;
  const int wn = (wave & 1) * 64;
  const int quad = lane >> 4;
  const int l16 = lane & 15;
  const int bm = blockIdx.y * 128;
  const int bn = blockIdx.x * 128;

  const signed char* Ag = xq + (size_t)bm * KD;
  const signed char* Bg = wq + (size_t)bn * KD;

  // staging: 512 chunks of 16B per tile; thread t does chunks t and t+256
  const int r0 = tid >> 2;            // 0..63
  const int c0 = (tid & 3) * 16;      // 0/16/32/48
  const signed char* agp0 = Ag + (size_t)r0 * KD + c0;
  const signed char* agp1 = Ag + (size_t)(r0 + 64) * KD + c0;
  const signed char* bgp0 = Bg + (size_t)r0 * KD + c0;
  const signed char* bgp1 = Bg + (size_t)(r0 + 64) * KD + c0;
  signed char* al0 = &As[r0 * 64 + c0];
  signed char* al1 = &As[(r0 + 64) * 64 + c0];
  signed char* bl0 = &Bs[r0 * 64 + c0];
  signed char* bl1 = &Bs[(r0 + 64) * 64 + c0];

  i32x4 acc[4][4];
#pragma unroll
  for (int i = 0; i < 4; ++i)
#pragma unroll
    for (int j = 0; j < 4; ++j) acc[i][j] = (i32x4){0, 0, 0, 0};

  for (int k0 = 0; k0 < KD; k0 += 64) {
    __syncthreads();
    *(i32x4*)al0 = *(const i32x4*)(agp0 + k0);
    *(i32x4*)al1 = *(const i32x4*)(agp1 + k0);
    *(i32x4*)bl0 = *(const i32x4*)(bgp0 + k0);
    *(i32x4*)bl1 = *(const i32x4*)(bgp1 + k0);
    __syncthreads();

    i32x4 af[4], bf[4];
#pragma unroll
    for (int mi = 0; mi < 4; ++mi)
      af[mi] = *(const i32x4*)&As[(wm + mi * 16 + l16) * 64 + quad * 16];
#pragma unroll
    for (int ni = 0; ni < 4; ++ni)
      bf[ni] = *(const i32x4*)&Bs[(wn + ni * 16 + l16) * 64 + quad * 16];
#pragma unroll
    for (int mi = 0; mi < 4; ++mi)
#pragma unroll
      for (int ni = 0; ni < 4; ++ni)
        acc[mi][ni] = __builtin_amdgcn_mfma_i32_16x16x64_i8(af[mi], bf[ni],
                                                            acc[mi][ni], 0, 0, 0);
  }

  const float alpha = alpha_p[0];
#pragma unroll
  for (int mi = 0; mi < 4; ++mi) {
#pragma unroll
    for (int r = 0; r < 4; ++r) {
      const int m = bm + wm + mi * 16 + quad * 4 + r;
      const float s = (alpha * gamma[m]) / 127.0f;
#pragma unroll
      for (int ni = 0; ni < 4; ++ni) {
        const int n = bn + wn + ni * 16 + l16;
        out[(size_t)m * ND + n] = (float)acc[mi][ni][r] * s;
      }
    }
  }
}

// --------------------------------------------------------------------------

extern "C" void kernel_launch(void* const* d_in, const int* in_sizes, int n_in,
                              void* d_out, int out_size, void* d_ws, size_t ws_size,
                              hipStream_t stream) {
  const float* x = (const float*)d_in[0];
  const float* w = (const float*)d_in[1];
  const float* nw = (const float*)d_in[2];
  float* out = (float*)d_out;

  char* ws = (char*)d_ws;
  signed char* xq = (signed char*)ws;
  signed char* wq = (signed char*)(ws + ((size_t)1 << 24));
  float* gamma = (float*)(ws + ((size_t)2 << 24));
  float* part = (float*)(ws + ((size_t)2 << 24) + 16384);
  float* alpha = (float*)(ws + ((size_t)2 << 24) + 32768);

  k_alpha_part<<<4096, 256, 0, stream>>>(w, part);
  k_alpha_final<<<1, 256, 0, stream>>>(part, alpha);
  k_quant_w<<<4096, 256, 0, stream>>>(w, alpha, wq);
  k_rmsnorm_quant<<<4096, 256, 0, stream>>>(x, nw, xq, gamma);
  dim3 g(ND / 128, MD / 128);
  k_gemm<<<g, 256, 0, stream>>>(xq, wq, gamma, alpha, out);
}

// Round 2
// 269.863 us; speedup vs baseline: 1.0418x; 1.0418x over previous
//
#include <hip/hip_runtime.h>
#include <cstdint>
#include <cstddef>

// FusedBitLinear: RMSNorm -> ternary W quant (absmean) -> int8 activation quant
// -> int GEMM (MFMA i8) -> rescale by alpha*gamma[m]/127.
//
// M=4096 tokens, K=4096, N=4096. fp32 in/out.
//
// ws layout:
//   [0, 16M)            xq   int8 [4096][4096]
//   [16M, 32M)          wq   int8 [4096][4096]
//   [32M, +16KB)        gamma float[4096]
//   [+16KB, +32KB)      alpha partials float[4096]
//   [+32KB, +4B)        alpha float[1]

#define KD 4096
#define MD 4096
#define ND 4096

typedef int i32x4 __attribute__((ext_vector_type(4)));

// async global->LDS, 16B per lane; lds dst must be wave-uniform base (+lane*16)
__device__ __forceinline__ void gl2lds16(const signed char* g, signed char* l) {
  __builtin_amdgcn_global_load_lds(
      (const __attribute__((address_space(1))) void*)g,
      (__attribute__((address_space(3))) void*)l, 16, 0, 0);
}

__device__ __forceinline__ float wave_sum(float v) {
#pragma unroll
  for (int off = 32; off; off >>= 1) v += __shfl_down(v, off, 64);
  return v;
}
__device__ __forceinline__ float wave_max(float v) {
#pragma unroll
  for (int off = 32; off; off >>= 1) v = fmaxf(v, __shfl_down(v, off, 64));
  return v;
}

// ---------------- alpha = max(mean(|W|), 1e-10) --------------------------

__global__ __launch_bounds__(256) void k_alpha_part(const float* __restrict__ w,
                                                    float* __restrict__ part) {
  __shared__ float red[4];
  const int tid = threadIdx.x;
  const float4* w4 = (const float4*)(w + (size_t)blockIdx.x * 4096);
  float s = 0.f;
#pragma unroll
  for (int i = 0; i < 4; ++i) {
    float4 v = w4[i * 256 + tid];
    s += fabsf(v.x) + fabsf(v.y) + fabsf(v.z) + fabsf(v.w);
  }
  s = wave_sum(s);
  if ((tid & 63) == 0) red[tid >> 6] = s;
  __syncthreads();
  if (tid == 0) part[blockIdx.x] = (red[0] + red[1]) + (red[2] + red[3]);
}

__global__ __launch_bounds__(256) void k_alpha_final(const float* __restrict__ part,
                                                     float* __restrict__ alpha) {
  __shared__ float red[4];
  const int tid = threadIdx.x;
  float s = 0.f;
#pragma unroll
  for (int i = 0; i < 16; ++i) s += part[i * 256 + tid];
  s = wave_sum(s);
  if ((tid & 63) == 0) red[tid >> 6] = s;
  __syncthreads();
  if (tid == 0)
    alpha[0] = fmaxf(((red[0] + red[1]) + (red[2] + red[3])) * (1.0f / 16777216.0f),
                     1e-10f);
}

// ---------------- w_q = clip(rint(w/alpha), -1, 1) as int8 ----------------

__global__ __launch_bounds__(256) void k_quant_w(const float* __restrict__ w,
                                                 const float* __restrict__ alpha_p,
                                                 signed char* __restrict__ wq) {
  const float alpha = alpha_p[0];
  const int tid = threadIdx.x;
  const float4* w4 = (const float4*)(w + (size_t)blockIdx.x * 4096);
  uint32_t* wqi = (uint32_t*)(wq + (size_t)blockIdx.x * 4096);
#pragma unroll
  for (int i = 0; i < 4; ++i) {
    const int f = i * 256 + tid;
    float4 v = w4[f];
    int q0 = (int)fminf(fmaxf(rintf(v.x / alpha), -1.f), 1.f);
    int q1 = (int)fminf(fmaxf(rintf(v.y / alpha), -1.f), 1.f);
    int q2 = (int)fminf(fmaxf(rintf(v.z / alpha), -1.f), 1.f);
    int q3 = (int)fminf(fmaxf(rintf(v.w / alpha), -1.f), 1.f);
    wqi[f] = (uint32_t)(q0 & 255) | ((uint32_t)(q1 & 255) << 8) |
             ((uint32_t)(q2 & 255) << 16) | ((uint32_t)(q3 & 255) << 24);
  }
}

// ------------- RMSNorm + gamma + int8 activation quant --------------------

__global__ __launch_bounds__(256) void k_rmsnorm_quant(const float* __restrict__ x,
                                                       const float* __restrict__ nw,
                                                       signed char* __restrict__ xq,
                                                       float* __restrict__ gamma) {
  __shared__ float red[4];
  __shared__ float red2[4];
  const int tid = threadIdx.x;
  const int row = blockIdx.x;
  const float4* x4 = (const float4*)(x + (size_t)row * 4096);
  const float4* n4 = (const float4*)nw;
  float4 xv[4], nv[4];
  float ss = 0.f;
#pragma unroll
  for (int i = 0; i < 4; ++i) {
    xv[i] = x4[i * 256 + tid];
    nv[i] = n4[i * 256 + tid];
    ss += xv[i].x * xv[i].x + xv[i].y * xv[i].y + xv[i].z * xv[i].z + xv[i].w * xv[i].w;
  }
  ss = wave_sum(ss);
  if ((tid & 63) == 0) red[tid >> 6] = ss;
  __syncthreads();
  const float tot = (red[0] + red[1]) + (red[2] + red[3]);
  const float rms = sqrtf(tot * (1.0f / 4096.0f) + 1e-6f);

  float4 xn[4];
  float mx = 0.f;
#pragma unroll
  for (int i = 0; i < 4; ++i) {
    xn[i].x = xv[i].x / rms * nv[i].x;
    xn[i].y = xv[i].y / rms * nv[i].y;
    xn[i].z = xv[i].z / rms * nv[i].z;
    xn[i].w = xv[i].w / rms * nv[i].w;
    mx = fmaxf(mx, fmaxf(fmaxf(fabsf(xn[i].x), fabsf(xn[i].y)),
                         fmaxf(fabsf(xn[i].z), fabsf(xn[i].w))));
  }
  mx = wave_max(mx);
  if ((tid & 63) == 0) red2[tid >> 6] = mx;
  __syncthreads();
  const float g = fmaxf(fmaxf(fmaxf(red2[0], red2[1]), fmaxf(red2[2], red2[3])),
                        1e-10f);
  if (tid == 0) gamma[row] = g;

  uint32_t* xqi = (uint32_t*)(xq + (size_t)row * 4096);
#pragma unroll
  for (int i = 0; i < 4; ++i) {
    const int f = i * 256 + tid;
    int q0 = (int)fminf(fmaxf(rintf(xn[i].x * 127.0f / g), -128.f), 127.f);
    int q1 = (int)fminf(fmaxf(rintf(xn[i].y * 127.0f / g), -128.f), 127.f);
    int q2 = (int)fminf(fmaxf(rintf(xn[i].z * 127.0f / g), -128.f), 127.f);
    int q3 = (int)fminf(fmaxf(rintf(xn[i].w * 127.0f / g), -128.f), 127.f);
    xqi[f] = (uint32_t)(q0 & 255) | ((uint32_t)(q1 & 255) << 8) |
             ((uint32_t)(q2 & 255) << 16) | ((uint32_t)(q3 & 255) << 24);
  }
}

// ------------- int8 GEMM: y[m,n] = (xq . wq^T) * alpha*gamma[m]/127 -------
// 128x128 block tile, BK=64, 4 waves (2x2), each wave 64x64 via 4x4 MFMA
// 16x16x64 i8. A/B frag: byte j of the 16 = k = quad*16 + j, m/n = lane&15.
// C/D: col = lane&15, row = quad*4 + reg (verified round 1).
//
// Staging via global_load_lds (16B/lane, wave-uniform LDS base + lane*16).
// XOR chunk swizzle: row r's 16B chunk c lives at LDS position c ^ ((r>>1)&3)
// -> fragment-read start banks 16*(l16&1) + 4*(quad^((l16>>1)&3)): all 8
// values, 2 lanes each = 2-way = conflict-free (m136).

__global__ __launch_bounds__(256) void k_gemm(const signed char* __restrict__ xq,
                                              const signed char* __restrict__ wq,
                                              const float* __restrict__ gamma,
                                              const float* __restrict__ alpha_p,
                                              float* __restrict__ out) {
  __shared__ __align__(16) signed char As[128 * 64];
  __shared__ __align__(16) signed char Bs[128 * 64];
  const int tid = threadIdx.x;
  const int lane = tid & 63;
  const int wave = tid >> 6;
  const int wm = (wave >> 1) * 64;
  const int wn = (wave & 1) * 64;
  const int quad = lane >> 4;
  const int l16 = lane & 15;
  const int bm = blockIdx.y * 128;
  const int bn = blockIdx.x * 128;

  const signed char* Ag = xq + (size_t)bm * KD;
  const signed char* Bg = wq + (size_t)bn * KD;

  // per-lane global source: row = wave*16 + (lane>>2), chunk swizzled so that
  // LDS position (lane&3) of that row holds chunk (lane&3)^((row>>1)&3)
  const int srow = wave * 16 + (lane >> 2);
  const int schunk = (lane & 3) ^ ((lane >> 3) & 3);
  const signed char* agp0 = Ag + (size_t)srow * KD + schunk * 16;
  const signed char* agp1 = Ag + (size_t)(srow + 64) * KD + schunk * 16;
  const signed char* bgp0 = Bg + (size_t)srow * KD + schunk * 16;
  const signed char* bgp1 = Bg + (size_t)(srow + 64) * KD + schunk * 16;
  // wave-uniform LDS bases (lane i auto-lands at base + i*16)
  signed char* la0 = &As[wave * 1024];
  signed char* la1 = &As[4096 + wave * 1024];
  signed char* lb0 = &Bs[wave * 1024];
  signed char* lb1 = &Bs[4096 + wave * 1024];

  i32x4 acc[4][4];
#pragma unroll
  for (int i = 0; i < 4; ++i)
#pragma unroll
    for (int j = 0; j < 4; ++j) acc[i][j] = (i32x4){0, 0, 0, 0};

  const int sw = (l16 >> 1) & 3;  // (row>>1)&3 for fragment rows
  const int apos = (quad ^ sw) * 16;

  for (int k0 = 0; k0 < KD; k0 += 64) {
    __syncthreads();
    gl2lds16(agp0 + k0, la0);
    gl2lds16(agp1 + k0, la1);
    gl2lds16(bgp0 + k0, lb0);
    gl2lds16(bgp1 + k0, lb1);
    __syncthreads();

    i32x4 af[4], bf[4];
#pragma unroll
    for (int mi = 0; mi < 4; ++mi)
      af[mi] = *(const i32x4*)&As[(wm + mi * 16 + l16) * 64 + apos];
#pragma unroll
    for (int ni = 0; ni < 4; ++ni)
      bf[ni] = *(const i32x4*)&Bs[(wn + ni * 16 + l16) * 64 + apos];
#pragma unroll
    for (int mi = 0; mi < 4; ++mi)
#pragma unroll
      for (int ni = 0; ni < 4; ++ni)
        acc[mi][ni] = __builtin_amdgcn_mfma_i32_16x16x64_i8(af[mi], bf[ni],
                                                            acc[mi][ni], 0, 0, 0);
  }

  const float alpha = alpha_p[0];
#pragma unroll
  for (int mi = 0; mi < 4; ++mi) {
#pragma unroll
    for (int r = 0; r < 4; ++r) {
      const int m = bm + wm + mi * 16 + quad * 4 + r;
      const float s = (alpha * gamma[m]) / 127.0f;
#pragma unroll
      for (int ni = 0; ni < 4; ++ni) {
        const int n = bn + wn + ni * 16 + l16;
        out[(size_t)m * ND + n] = (float)acc[mi][ni][r] * s;
      }
    }
  }
}

// --------------------------------------------------------------------------

extern "C" void kernel_launch(void* const* d_in, const int* in_sizes, int n_in,
                              void* d_out, int out_size, void* d_ws, size_t ws_size,
                              hipStream_t stream) {
  const float* x = (const float*)d_in[0];
  const float* w = (const float*)d_in[1];
  const float* nw = (const float*)d_in[2];
  float* out = (float*)d_out;

  char* ws = (char*)d_ws;
  signed char* xq = (signed char*)ws;
  signed char* wq = (signed char*)(ws + ((size_t)1 << 24));
  float* gamma = (float*)(ws + ((size_t)2 << 24));
  float* part = (float*)(ws + ((size_t)2 << 24) + 16384);
  float* alpha = (float*)(ws + ((size_t)2 << 24) + 32768);

  k_alpha_part<<<4096, 256, 0, stream>>>(w, part);
  k_alpha_final<<<1, 256, 0, stream>>>(part, alpha);
  k_quant_w<<<4096, 256, 0, stream>>>(w, alpha, wq);
  k_rmsnorm_quant<<<4096, 256, 0, stream>>>(x, nw, xq, gamma);
  dim3 g(ND / 128, MD / 128);
  k_gemm<<<g, 256, 0, stream>>>(xq, wq, gamma, alpha, out);
}

// Round 3
// 244.084 us; speedup vs baseline: 1.1518x; 1.1056x over previous
//
#include <hip/hip_runtime.h>
#include <cstdint>
#include <cstddef>

// FusedBitLinear: RMSNorm -> ternary W quant (absmean) -> int8 activation quant
// -> int GEMM (MFMA i8) -> rescale by alpha*gamma[m]/127.
//
// M=4096 tokens, K=4096, N=4096. fp32 in/out.
//
// ws layout:
//   [0, 16M)            xq   int8 [4096][4096]
//   [16M, 32M)          wq   int8 [4096][4096]
//   [32M, +16KB)        gamma float[4096]
//   [+16KB, +32KB)      alpha partials float[4096]
//   [+32KB, +4B)        alpha float[1]

#define KD 4096
#define MD 4096
#define ND 4096

typedef int i32x4 __attribute__((ext_vector_type(4)));

// async global->LDS, 16B per lane; lds dst is wave-uniform base (+lane*16)
__device__ __forceinline__ void gl2lds16(const signed char* g, signed char* l) {
  __builtin_amdgcn_global_load_lds(
      (const __attribute__((address_space(1))) void*)g,
      (__attribute__((address_space(3))) void*)l, 16, 0, 0);
}

__device__ __forceinline__ float wave_sum(float v) {
#pragma unroll
  for (int off = 32; off; off >>= 1) v += __shfl_down(v, off, 64);
  return v;
}
__device__ __forceinline__ float wave_max(float v) {
#pragma unroll
  for (int off = 32; off; off >>= 1) v = fmaxf(v, __shfl_down(v, off, 64));
  return v;
}

// ---------------- pass 1: per-row |W| partial sums ------------------------

__global__ __launch_bounds__(256) void k_alpha_part(const float* __restrict__ w,
                                                    float* __restrict__ part) {
  __shared__ float red[4];
  const int tid = threadIdx.x;
  const float4* w4 = (const float4*)(w + (size_t)blockIdx.x * 4096);
  float s = 0.f;
#pragma unroll
  for (int i = 0; i < 4; ++i) {
    float4 v = w4[i * 256 + tid];
    s += fabsf(v.x) + fabsf(v.y) + fabsf(v.z) + fabsf(v.w);
  }
  s = wave_sum(s);
  if ((tid & 63) == 0) red[tid >> 6] = s;
  __syncthreads();
  if (tid == 0) part[blockIdx.x] = (red[0] + red[1]) + (red[2] + red[3]);
}

// ---------------- pass 2: fused quantization ------------------------------
// blocks [0,4096): recompute alpha from partials (bit-identical reduction in
// every block -> deterministic), quantize W row bid. Block 0 publishes alpha.
// blocks [4096,8192): RMSNorm + gamma + int8 quant of x row (bid-4096).

__global__ __launch_bounds__(256) void k_quant_all(const float* __restrict__ w,
                                                   const float* __restrict__ x,
                                                   const float* __restrict__ nw,
                                                   const float* __restrict__ part,
                                                   signed char* __restrict__ wq,
                                                   signed char* __restrict__ xq,
                                                   float* __restrict__ gamma,
                                                   float* __restrict__ alpha_out) {
  const int tid = threadIdx.x;
  const int bid = blockIdx.x;
  __shared__ float red[4];
  __shared__ float red2[4];

  if (bid < 4096) {
    // ---- alpha (same reduction order as round 2's k_alpha_final) ----
    float s = 0.f;
#pragma unroll
    for (int i = 0; i < 16; ++i) s += part[i * 256 + tid];
    s = wave_sum(s);
    if ((tid & 63) == 0) red[tid >> 6] = s;
    __syncthreads();
    const float alpha =
        fmaxf(((red[0] + red[1]) + (red[2] + red[3])) * (1.0f / 16777216.0f),
              1e-10f);
    if (bid == 0 && tid == 0) alpha_out[0] = alpha;

    // ---- quantize W row ----
    const float4* w4 = (const float4*)(w + (size_t)bid * 4096);
    uint32_t* wqi = (uint32_t*)(wq + (size_t)bid * 4096);
#pragma unroll
    for (int i = 0; i < 4; ++i) {
      const int f = i * 256 + tid;
      float4 v = w4[f];
      int q0 = (int)fminf(fmaxf(rintf(v.x / alpha), -1.f), 1.f);
      int q1 = (int)fminf(fmaxf(rintf(v.y / alpha), -1.f), 1.f);
      int q2 = (int)fminf(fmaxf(rintf(v.z / alpha), -1.f), 1.f);
      int q3 = (int)fminf(fmaxf(rintf(v.w / alpha), -1.f), 1.f);
      wqi[f] = (uint32_t)(q0 & 255) | ((uint32_t)(q1 & 255) << 8) |
               ((uint32_t)(q2 & 255) << 16) | ((uint32_t)(q3 & 255) << 24);
    }
  } else {
    // ---- RMSNorm + gamma + quantize x row ----
    const int row = bid - 4096;
    const float4* x4 = (const float4*)(x + (size_t)row * 4096);
    const float4* n4 = (const float4*)nw;
    float4 xv[4], nv[4];
    float ss = 0.f;
#pragma unroll
    for (int i = 0; i < 4; ++i) {
      xv[i] = x4[i * 256 + tid];
      nv[i] = n4[i * 256 + tid];
      ss += xv[i].x * xv[i].x + xv[i].y * xv[i].y + xv[i].z * xv[i].z +
            xv[i].w * xv[i].w;
    }
    ss = wave_sum(ss);
    if ((tid & 63) == 0) red[tid >> 6] = ss;
    __syncthreads();
    const float tot = (red[0] + red[1]) + (red[2] + red[3]);
    const float rms = sqrtf(tot * (1.0f / 4096.0f) + 1e-6f);

    float4 xn[4];
    float mx = 0.f;
#pragma unroll
    for (int i = 0; i < 4; ++i) {
      xn[i].x = xv[i].x / rms * nv[i].x;
      xn[i].y = xv[i].y / rms * nv[i].y;
      xn[i].z = xv[i].z / rms * nv[i].z;
      xn[i].w = xv[i].w / rms * nv[i].w;
      mx = fmaxf(mx, fmaxf(fmaxf(fabsf(xn[i].x), fabsf(xn[i].y)),
                           fmaxf(fabsf(xn[i].z), fabsf(xn[i].w))));
    }
    mx = wave_max(mx);
    if ((tid & 63) == 0) red2[tid >> 6] = mx;
    __syncthreads();
    const float g = fmaxf(
        fmaxf(fmaxf(red2[0], red2[1]), fmaxf(red2[2], red2[3])), 1e-10f);
    if (tid == 0) gamma[row] = g;

    uint32_t* xqi = (uint32_t*)(xq + (size_t)row * 4096);
#pragma unroll
    for (int i = 0; i < 4; ++i) {
      const int f = i * 256 + tid;
      int q0 = (int)fminf(fmaxf(rintf(xn[i].x * 127.0f / g), -128.f), 127.f);
      int q1 = (int)fminf(fmaxf(rintf(xn[i].y * 127.0f / g), -128.f), 127.f);
      int q2 = (int)fminf(fmaxf(rintf(xn[i].z * 127.0f / g), -128.f), 127.f);
      int q3 = (int)fminf(fmaxf(rintf(xn[i].w * 127.0f / g), -128.f), 127.f);
      xqi[f] = (uint32_t)(q0 & 255) | ((uint32_t)(q1 & 255) << 8) |
               ((uint32_t)(q2 & 255) << 16) | ((uint32_t)(q3 & 255) << 24);
    }
  }
}

// ------------- int8 GEMM: y[m,n] = (xq . wq^T) * alpha*gamma[m]/127 -------
// 128x128 block tile, BK=128 (32 KB LDS), 4 waves (2x2), each wave 64x64 via
// 4x4 MFMA 16x16x64 i8, two K-slices per staged tile -> 32 MFMA per barrier.
// A/B frag: byte j of the 16 = k = ks*64 + quad*16 + j, m/n = lane&15.
// C/D: col = lane&15, row = quad*4 + reg (verified round 1).
//
// Swizzle: LDS chunk-position p of row R holds source chunk p ^ (R&7).
// Fragment read position (ks*4+quad) ^ (l16&7) -> 8 distinct 16B bank groups,
// 8 lanes each: the same conflict-free structure round 2 measured at 0.

__global__ __launch_bounds__(256) void k_gemm(const signed char* __restrict__ xq,
                                              const signed char* __restrict__ wq,
                                              const float* __restrict__ gamma,
                                              const float* __restrict__ alpha_p,
                                              float* __restrict__ out) {
  __shared__ __align__(16) signed char As[128 * 128];
  __shared__ __align__(16) signed char Bs[128 * 128];
  const int tid = threadIdx.x;
  const int lane = tid & 63;
  const int wave = tid >> 6;
  const int wm = (wave >> 1) * 64;
  const int wn = (wave & 1) * 64;
  const int quad = lane >> 4;
  const int l16 = lane & 15;
  const int bm = blockIdx.y * 128;
  const int bn = blockIdx.x * 128;

  const signed char* Ag = xq + (size_t)bm * KD;
  const signed char* Bg = wq + (size_t)bn * KD;

  // staging: 16 wave-instructions per tile; wave w slot i covers rows
  // [i*32 + w*8, +8) x 8 chunks. lane l -> row +(l>>3), LDS pos (l&7),
  // source chunk (l&7) ^ (l>>3).
  const int lr = lane >> 3;
  const int sc = (lane & 7) ^ lr;
  const signed char* agp[4];
  const signed char* bgp[4];
  signed char* la[4];
  signed char* lb[4];
#pragma unroll
  for (int i = 0; i < 4; ++i) {
    const int R = i * 32 + wave * 8 + lr;
    agp[i] = Ag + (size_t)R * KD + sc * 16;
    bgp[i] = Bg + (size_t)R * KD + sc * 16;
    la[i] = &As[(i * 32 + wave * 8) * 128];
    lb[i] = &Bs[(i * 32 + wave * 8) * 128];
  }

  i32x4 acc[4][4];
#pragma unroll
  for (int i = 0; i < 4; ++i)
#pragma unroll
    for (int j = 0; j < 4; ++j) acc[i][j] = (i32x4){0, 0, 0, 0};

  const int swz = l16 & 7;

  for (int k0 = 0; k0 < KD; k0 += 128) {
    __syncthreads();
#pragma unroll
    for (int i = 0; i < 4; ++i) gl2lds16(agp[i] + k0, la[i]);
#pragma unroll
    for (int i = 0; i < 4; ++i) gl2lds16(bgp[i] + k0, lb[i]);
    __syncthreads();

#pragma unroll
    for (int ks = 0; ks < 2; ++ks) {
      const int pos = ((ks * 4 + quad) ^ swz) * 16;
      i32x4 af[4], bf[4];
#pragma unroll
      for (int mi = 0; mi < 4; ++mi)
        af[mi] = *(const i32x4*)&As[(wm + mi * 16 + l16) * 128 + pos];
#pragma unroll
      for (int ni = 0; ni < 4; ++ni)
        bf[ni] = *(const i32x4*)&Bs[(wn + ni * 16 + l16) * 128 + pos];
#pragma unroll
      for (int mi = 0; mi < 4; ++mi)
#pragma unroll
        for (int ni = 0; ni < 4; ++ni)
          acc[mi][ni] = __builtin_amdgcn_mfma_i32_16x16x64_i8(af[mi], bf[ni],
                                                              acc[mi][ni], 0, 0, 0);
    }
  }

  const float alpha = alpha_p[0];
#pragma unroll
  for (int mi = 0; mi < 4; ++mi) {
#pragma unroll
    for (int r = 0; r < 4; ++r) {
      const int m = bm + wm + mi * 16 + quad * 4 + r;
      const float s = (alpha * gamma[m]) / 127.0f;
#pragma unroll
      for (int ni = 0; ni < 4; ++ni) {
        const int n = bn + wn + ni * 16 + l16;
        out[(size_t)m * ND + n] = (float)acc[mi][ni][r] * s;
      }
    }
  }
}

// --------------------------------------------------------------------------

extern "C" void kernel_launch(void* const* d_in, const int* in_sizes, int n_in,
                              void* d_out, int out_size, void* d_ws, size_t ws_size,
                              hipStream_t stream) {
  const float* x = (const float*)d_in[0];
  const float* w = (const float*)d_in[1];
  const float* nw = (const float*)d_in[2];
  float* out = (float*)d_out;

  char* ws = (char*)d_ws;
  signed char* xq = (signed char*)ws;
  signed char* wq = (signed char*)(ws + ((size_t)1 << 24));
  float* gamma = (float*)(ws + ((size_t)2 << 24));
  float* part = (float*)(ws + ((size_t)2 << 24) + 16384);
  float* alpha = (float*)(ws + ((size_t)2 << 24) + 32768);

  k_alpha_part<<<4096, 256, 0, stream>>>(w, part);
  k_quant_all<<<8192, 256, 0, stream>>>(w, x, nw, part, wq, xq, gamma, alpha);
  dim3 g(ND / 128, MD / 128);
  k_gemm<<<g, 256, 0, stream>>>(xq, wq, gamma, alpha, out);
}